// Round 1
// baseline (1108.768 us; speedup 1.0000x reference)
//
#include <hip/hip_runtime.h>

#define HH 96
#define WW 96
#define HW 9216
#define CIN 64
#define COUT 64
#define NB 8

// ---------------------------------------------------------------------------
// Kernel T: transpose weight (co, c, k) -> wT (k, c, co) so that the main
// kernel's inner-loop weight reads are wave-uniform + contiguous (s_load).
// ---------------------------------------------------------------------------
__global__ __launch_bounds__(256) void wtrans_kernel(const float* __restrict__ Wsrc,
                                                     float* __restrict__ wT) {
    int t  = blockIdx.x * 256 + threadIdx.x;   // t < 9*64*64 = 36864
    int co = t & 63;
    int c  = (t >> 6) & 63;
    int k  = t >> 12;                           // 0..8
    wT[t] = Wsrc[(co * 64 + c) * 9 + k];
}

// ---------------------------------------------------------------------------
// Kernel A: offset conv. out[b,j,h,w] = off_b[j] + sum_{c,r,s} x[b,c,h-1+r,w-1+s]*off_w[j,c,r,s]
// thread = one pixel, 18 accumulators. Weights read at uniform addresses.
// ---------------------------------------------------------------------------
__global__ __launch_bounds__(256) void offs_kernel(const float* __restrict__ x,
                                                   const float* __restrict__ ow,
                                                   const float* __restrict__ ob,
                                                   float* __restrict__ off) {
    int tid = blockIdx.x * 256 + threadIdx.x;   // exactly 73728 threads
    int b   = tid / HW;
    int rem = tid % HW;
    int h   = rem / WW;
    int w   = rem % WW;

    float acc[18];
#pragma unroll
    for (int j = 0; j < 18; ++j) acc[j] = ob[j];

    const float* xb = x + b * CIN * HW;

    for (int c = 0; c < CIN; ++c) {
        float v[9];
#pragma unroll
        for (int r = 0; r < 3; ++r) {
            int  iy = h - 1 + r;
            bool ry = (iy >= 0) && (iy < HH);
#pragma unroll
            for (int s = 0; s < 3; ++s) {
                int  ix = w - 1 + s;
                bool cx = (ix >= 0) && (ix < WW);
                v[r * 3 + s] = (ry && cx) ? xb[c * HW + iy * WW + ix] : 0.f;
            }
        }
#pragma unroll
        for (int j = 0; j < 18; ++j) {
            const float* wp = ow + (j * 64 + c) * 9;   // uniform -> s_load
            float a = acc[j];
#pragma unroll
            for (int q = 0; q < 9; ++q) a = fmaf(v[q], wp[q], a);
            acc[j] = a;
        }
    }
#pragma unroll
    for (int j = 0; j < 18; ++j) off[(b * 18 + j) * HW + rem] = acc[j];
}

// ---------------------------------------------------------------------------
// Kernel B: bilinear sampling + main contraction.
// Block = 256 threads = 128 pixels x 2 c-halves (c-half is WAVE-uniform so
// weight loads stay scalar). acc[64] per thread; LDS reduce across halves.
// ---------------------------------------------------------------------------
__global__ __launch_bounds__(256) void deform_main(const float* __restrict__ x,
                                                   const float* __restrict__ wT,
                                                   const float* __restrict__ bias,
                                                   const float* __restrict__ off,
                                                   float* __restrict__ out) {
    __shared__ float red[128 * 65];   // pad 65: writes are 2-way bank-aliased (free)

    int lane  = threadIdx.x & 63;
    int wid   = threadIdx.x >> 6;
    int chalf = wid >> 1;                       // wave-uniform: 0 or 1
    int pixb  = ((wid & 1) << 6) | lane;        // 0..127
    int pixel = blockIdx.x * 128 + pixb;        // grid covers 73728 exactly
    int b     = pixel / HW;
    int rem   = pixel % HW;
    int h     = rem / WW;
    int w     = rem % WW;

    const float* xb   = x + (b * CIN + chalf * 32) * HW;
    const float* offb = off + b * 18 * HW + rem;

    float acc[COUT];
#pragma unroll
    for (int i = 0; i < COUT; ++i) acc[i] = 0.f;

    for (int k = 0; k < 9; ++k) {
        int r = k / 3, s = k - r * 3;
        float offy = offb[(2 * k) * HW];
        float offx = offb[(2 * k + 1) * HW];
        // reference: sy = h + 1 + (r-1) + offy  (NO pad subtraction in ref!)
        float sy = (float)(h + r) + offy;
        float sx = (float)(w + s) + offx;
        float fy = floorf(sy), fx = floorf(sx);
        int   y0 = (int)fy, x0 = (int)fx;
        int   y1 = y0 + 1, x1 = x0 + 1;
        float wy1 = sy - fy, wx1 = sx - fx;
        float wy0 = 1.f - wy1, wx0 = 1.f - wx1;

        float m00 = (y0 >= 0 && y0 < HH && x0 >= 0 && x0 < WW) ? 1.f : 0.f;
        float m01 = (y0 >= 0 && y0 < HH && x1 >= 0 && x1 < WW) ? 1.f : 0.f;
        float m10 = (y1 >= 0 && y1 < HH && x0 >= 0 && x0 < WW) ? 1.f : 0.f;
        float m11 = (y1 >= 0 && y1 < HH && x1 >= 0 && x1 < WW) ? 1.f : 0.f;

        int cy0 = min(max(y0, 0), HH - 1), cy1 = min(max(y1, 0), HH - 1);
        int cx0 = min(max(x0, 0), WW - 1), cx1 = min(max(x1, 0), WW - 1);
        int i00 = cy0 * WW + cx0, i01 = cy0 * WW + cx1;
        int i10 = cy1 * WW + cx0, i11 = cy1 * WW + cx1;
        float w00 = wy0 * wx0 * m00, w01 = wy0 * wx1 * m01;
        float w10 = wy1 * wx0 * m10, w11 = wy1 * wx1 * m11;

        const float* wk = wT + (k * 64 + chalf * 32) * 64;   // wave-uniform
#pragma unroll 2
        for (int cc = 0; cc < 32; ++cc) {
            const float* xc   = xb + cc * HW;
            float sval = xc[i00] * w00 + xc[i01] * w01 + xc[i10] * w10 + xc[i11] * w11;
            const float* wrow = wk + cc * 64;                // uniform -> s_load
#pragma unroll
            for (int co = 0; co < COUT; ++co)
                acc[co] = fmaf(sval, wrow[co], acc[co]);
        }
    }

    if (chalf == 1) {
#pragma unroll
        for (int co = 0; co < COUT; ++co) red[pixb * 65 + co] = acc[co];
    }
    __syncthreads();
    if (chalf == 0) {
        float* ob = out + b * COUT * HW + rem;
#pragma unroll
        for (int co = 0; co < COUT; ++co) {
            ob[co * HW] = acc[co] + red[pixb * 65 + co] + bias[co];
        }
    }
}

// ---------------------------------------------------------------------------
extern "C" void kernel_launch(void* const* d_in, const int* in_sizes, int n_in,
                              void* d_out, int out_size, void* d_ws, size_t ws_size,
                              hipStream_t stream) {
    const float* x      = (const float*)d_in[0];   // 8*64*96*96
    const float* weight = (const float*)d_in[1];   // 64*64*3*3
    const float* bias   = (const float*)d_in[2];   // 64
    const float* off_w  = (const float*)d_in[3];   // 18*64*3*3
    const float* off_b  = (const float*)d_in[4];   // 18
    float* out = (float*)d_out;                    // 8*64*96*96

    float* offbuf = (float*)d_ws;                  // 8*18*9216 = 1,327,104 floats
    float* wT     = offbuf + NB * 18 * HW;         // 36,864 floats (total ws use ~5.5 MB)

    hipLaunchKernelGGL(wtrans_kernel, dim3(144), dim3(256), 0, stream, weight, wT);
    hipLaunchKernelGGL(offs_kernel,   dim3(288), dim3(256), 0, stream, x, off_w, off_b, offbuf);
    hipLaunchKernelGGL(deform_main,   dim3(576), dim3(256), 0, stream, x, wT, bias, offbuf, out);
}

// Round 2
// 245.358 us; speedup vs baseline: 4.5190x; 4.5190x over previous
//
#include <hip/hip_runtime.h>

#define HH 96
#define WW 96
#define HW 9216
#define CIN 64
#define COUT 64
#define NB 8

// ---------------------------------------------------------------------------
// Kernel T: transpose weight (co, c, k) -> wT (k, c, co): main kernel stages
// contiguous 64x64 k-slices into LDS.
// ---------------------------------------------------------------------------
__global__ __launch_bounds__(256) void wtrans_kernel(const float* __restrict__ Wsrc,
                                                     float* __restrict__ wT) {
    int t  = blockIdx.x * 256 + threadIdx.x;   // t < 9*64*64 = 36864
    int co = t & 63;
    int c  = (t >> 6) & 63;
    int k  = t >> 12;                           // 0..8
    wT[t] = Wsrc[(co * 64 + c) * 9 + k];
}

// ---------------------------------------------------------------------------
// Kernel X: transpose x NCHW -> NHWC (xt[b][p][c]) so bilinear corners are
// 64 contiguous floats (vector loads instead of strided gathers).
// ---------------------------------------------------------------------------
__global__ __launch_bounds__(256) void xpose_kernel(const float* __restrict__ x,
                                                    float* __restrict__ xt) {
    __shared__ float T[64][65];                 // pad: conflict-free col reads
    int bid   = blockIdx.x;                     // 8*144 = 1152
    int b     = bid / 144;
    int pbase = (bid % 144) * 64;
    int t     = threadIdx.x;
    int pl    = t & 63;
    int q     = t >> 6;                         // 0..3
#pragma unroll
    for (int i = 0; i < 16; ++i) {
        int c = q * 16 + i;
        T[c][pl] = x[((size_t)b * 64 + c) * HW + pbase + pl];
    }
    __syncthreads();
#pragma unroll
    for (int i = 0; i < 16; ++i) {
        int p = q * 16 + i;
        xt[((size_t)(b * HW + pbase + p)) * 64 + pl] = T[pl][p];
    }
}

// ---------------------------------------------------------------------------
// Kernel A: offset conv, c split 4 ways for occupancy (1152 blocks).
// Reads original NCHW x (perfectly coalesced); weights via scalar path.
// ---------------------------------------------------------------------------
__global__ __launch_bounds__(256) void offs_kernel(const float* __restrict__ x,
                                                   const float* __restrict__ ow,
                                                   const float* __restrict__ ob,
                                                   float* __restrict__ off) {
    __shared__ float red[3][18][64];
    int bid   = blockIdx.x;                     // 1152
    int b     = bid / 144;
    int pbase = (bid % 144) * 64;
    int t     = threadIdx.x;
    int pl    = t & 63;
    int cq    = __builtin_amdgcn_readfirstlane(t >> 6);   // wave-uniform 0..3
    int rem   = pbase + pl;
    int h     = rem / WW;
    int w     = rem % WW;

    float acc[18];
#pragma unroll
    for (int j = 0; j < 18; ++j) acc[j] = (cq == 0) ? ob[j] : 0.f;

    const float* xb = x + ((size_t)b * CIN + cq * 16) * HW;

    for (int c = 0; c < 16; ++c) {
        float v[9];
#pragma unroll
        for (int r = 0; r < 3; ++r) {
            int  iy = h - 1 + r;
            bool ry = (iy >= 0) && (iy < HH);
#pragma unroll
            for (int s = 0; s < 3; ++s) {
                int  ix = w - 1 + s;
                bool cx = (ix >= 0) && (ix < WW);
                v[r * 3 + s] = (ry && cx) ? xb[c * HW + iy * WW + ix] : 0.f;
            }
        }
#pragma unroll
        for (int j = 0; j < 18; ++j) {
            const float* wp = ow + ((j * 64) + (cq * 16 + c)) * 9;  // scalar addr
            float a = acc[j];
#pragma unroll
            for (int q = 0; q < 9; ++q) a = fmaf(v[q], wp[q], a);
            acc[j] = a;
        }
    }

    if (cq != 0) {
#pragma unroll
        for (int j = 0; j < 18; ++j) red[cq - 1][j][pl] = acc[j];
    }
    __syncthreads();
    if (cq == 0) {
#pragma unroll
        for (int j = 0; j < 18; ++j) {
            float a = acc[j] + red[0][j][pl] + red[1][j][pl] + red[2][j][pl];
            off[((size_t)b * 18 + j) * HW + rem] = a;
        }
    }
}

// ---------------------------------------------------------------------------
// Kernel B: implicit GEMM. Block = 64 px x 64 co. Per k: sample S[64c][64px]
// into LDS (NHWC vector loads) + stage Wk[64c][64co], then 4x4 register-
// blocked outer product over cc.
// ---------------------------------------------------------------------------
__global__ __launch_bounds__(256) void deform_main(const float* __restrict__ xt,
                                                   const float* __restrict__ wT,
                                                   const float* __restrict__ bias,
                                                   const float* __restrict__ off,
                                                   float* __restrict__ out) {
    __shared__ float S[64][64];     // [c][px]
    __shared__ float Wk[64][64];    // [c][co]

    int bid   = blockIdx.x;                     // 1152
    int b     = bid / 144;
    int pbase = (bid % 144) * 64;
    int t     = threadIdx.x;

    // sampling role
    int pl = t & 63;
    int cg = __builtin_amdgcn_readfirstlane(t >> 6);   // 0..3 (16 c each)
    int c0 = cg * 16;
    int px = pbase + pl;
    int h  = px / WW;
    int w  = px % WW;
    const float* offb = off + (size_t)b * 18 * HW + px;
    const float* xb   = xt + (size_t)b * HW * 64;

    // gemm role: 4 co x 4 px per thread
    int px4 = (t & 15) * 4;
    int co4 = (t >> 4) * 4;

    float acc[4][4];
#pragma unroll
    for (int i = 0; i < 4; ++i)
#pragma unroll
        for (int j = 0; j < 4; ++j) acc[i][j] = 0.f;

    for (int k = 0; k < 9; ++k) {
        // ---- phase 1: sample S[c0..c0+16)[pl] ----
        int   r = k / 3, s = k - r * 3;
        float offy = offb[(2 * k) * HW];
        float offx = offb[(2 * k + 1) * HW];
        float sy = (float)(h + r) + offy;      // ref: h + 1 + (r-1) + offy
        float sx = (float)(w + s) + offx;
        float fy = floorf(sy), fx = floorf(sx);
        int   y0 = (int)fy, x0 = (int)fx;
        int   y1 = y0 + 1, x1 = x0 + 1;
        float wy1 = sy - fy, wx1 = sx - fx;
        float wy0 = 1.f - wy1, wx0 = 1.f - wx1;

        float m00 = (y0 >= 0 && y0 < HH && x0 >= 0 && x0 < WW) ? 1.f : 0.f;
        float m01 = (y0 >= 0 && y0 < HH && x1 >= 0 && x1 < WW) ? 1.f : 0.f;
        float m10 = (y1 >= 0 && y1 < HH && x0 >= 0 && x0 < WW) ? 1.f : 0.f;
        float m11 = (y1 >= 0 && y1 < HH && x1 >= 0 && x1 < WW) ? 1.f : 0.f;

        int cy0 = min(max(y0, 0), HH - 1), cy1 = min(max(y1, 0), HH - 1);
        int cx0 = min(max(x0, 0), WW - 1), cx1 = min(max(x1, 0), WW - 1);
        float w00 = wy0 * wx0 * m00, w01 = wy0 * wx1 * m01;
        float w10 = wy1 * wx0 * m10, w11 = wy1 * wx1 * m11;

        const float* p00 = xb + (size_t)(cy0 * WW + cx0) * 64 + c0;
        const float* p01 = xb + (size_t)(cy0 * WW + cx1) * 64 + c0;
        const float* p10 = xb + (size_t)(cy1 * WW + cx0) * 64 + c0;
        const float* p11 = xb + (size_t)(cy1 * WW + cx1) * 64 + c0;

#pragma unroll
        for (int i = 0; i < 4; ++i) {           // 4 c per chunk, 4 chunks = 16 c
            float4 v00 = *(const float4*)(p00 + i * 4);
            float4 v01 = *(const float4*)(p01 + i * 4);
            float4 v10 = *(const float4*)(p10 + i * 4);
            float4 v11 = *(const float4*)(p11 + i * 4);
            float r0 = w00 * v00.x + w01 * v01.x + w10 * v10.x + w11 * v11.x;
            float r1 = w00 * v00.y + w01 * v01.y + w10 * v10.y + w11 * v11.y;
            float r2 = w00 * v00.z + w01 * v01.z + w10 * v10.z + w11 * v11.z;
            float r3 = w00 * v00.w + w01 * v01.w + w10 * v10.w + w11 * v11.w;
            S[c0 + i * 4 + 0][pl] = r0;
            S[c0 + i * 4 + 1][pl] = r1;
            S[c0 + i * 4 + 2][pl] = r2;
            S[c0 + i * 4 + 3][pl] = r3;
        }

        // ---- stage Wk (4096 floats, 16 per thread) ----
        {
            const float4* src = (const float4*)(wT + (size_t)k * 4096);
            float4*       dst = (float4*)&Wk[0][0];
#pragma unroll
            for (int i = 0; i < 4; ++i) dst[t * 4 + i] = src[t * 4 + i];
        }
        __syncthreads();

        // ---- phase 2: GEMM over cc ----
#pragma unroll 4
        for (int cc = 0; cc < 64; ++cc) {
            float4 a  = *(const float4*)&S[cc][px4];
            float4 wv = *(const float4*)&Wk[cc][co4];
            acc[0][0] = fmaf(wv.x, a.x, acc[0][0]);
            acc[0][1] = fmaf(wv.x, a.y, acc[0][1]);
            acc[0][2] = fmaf(wv.x, a.z, acc[0][2]);
            acc[0][3] = fmaf(wv.x, a.w, acc[0][3]);
            acc[1][0] = fmaf(wv.y, a.x, acc[1][0]);
            acc[1][1] = fmaf(wv.y, a.y, acc[1][1]);
            acc[1][2] = fmaf(wv.y, a.z, acc[1][2]);
            acc[1][3] = fmaf(wv.y, a.w, acc[1][3]);
            acc[2][0] = fmaf(wv.z, a.x, acc[2][0]);
            acc[2][1] = fmaf(wv.z, a.y, acc[2][1]);
            acc[2][2] = fmaf(wv.z, a.z, acc[2][2]);
            acc[2][3] = fmaf(wv.z, a.w, acc[2][3]);
            acc[3][0] = fmaf(wv.w, a.x, acc[3][0]);
            acc[3][1] = fmaf(wv.w, a.y, acc[3][1]);
            acc[3][2] = fmaf(wv.w, a.z, acc[3][2]);
            acc[3][3] = fmaf(wv.w, a.w, acc[3][3]);
        }
        __syncthreads();
    }

    // ---- epilogue: 4 co x 4 px, contiguous float4 stores ----
#pragma unroll
    for (int i = 0; i < 4; ++i) {
        int   co = co4 + i;
        float bv = bias[co];
        float4 r;
        r.x = acc[i][0] + bv;
        r.y = acc[i][1] + bv;
        r.z = acc[i][2] + bv;
        r.w = acc[i][3] + bv;
        *(float4*)(out + ((size_t)b * COUT + co) * HW + pbase + px4) = r;
    }
}

// ---------------------------------------------------------------------------
extern "C" void kernel_launch(void* const* d_in, const int* in_sizes, int n_in,
                              void* d_out, int out_size, void* d_ws, size_t ws_size,
                              hipStream_t stream) {
    const float* x      = (const float*)d_in[0];   // 8*64*96*96
    const float* weight = (const float*)d_in[1];   // 64*64*3*3
    const float* bias   = (const float*)d_in[2];   // 64
    const float* off_w  = (const float*)d_in[3];   // 18*64*3*3
    const float* off_b  = (const float*)d_in[4];   // 18
    float* out = (float*)d_out;                    // 8*64*96*96

    float* offbuf = (float*)d_ws;                        // 1,327,104 floats
    float* wT     = offbuf + (size_t)NB * 18 * HW;       // 36,864 floats
    float* xt     = wT + 9 * 64 * 64;                    // 4,718,592 floats (~24.3 MB total)

    hipLaunchKernelGGL(wtrans_kernel, dim3(144),  dim3(256), 0, stream, weight, wT);
    hipLaunchKernelGGL(xpose_kernel,  dim3(1152), dim3(256), 0, stream, x, xt);
    hipLaunchKernelGGL(offs_kernel,   dim3(1152), dim3(256), 0, stream, x, off_w, off_b, offbuf);
    hipLaunchKernelGGL(deform_main,   dim3(1152), dim3(256), 0, stream, xt, wT, bias, offbuf, out);
}

// Round 3
// 241.021 us; speedup vs baseline: 4.6003x; 1.0180x over previous
//
#include <hip/hip_runtime.h>

#define HH 96
#define WW 96
#define HW 9216
#define CIN 64
#define COUT 64
#define NB 8

// ---------------------------------------------------------------------------
// Kernel T: transpose weight (co, c, k) -> wT (k, c, co).
// ---------------------------------------------------------------------------
__global__ __launch_bounds__(256) void wtrans_kernel(const float* __restrict__ Wsrc,
                                                     float* __restrict__ wT) {
    int t  = blockIdx.x * 256 + threadIdx.x;   // t < 9*64*64 = 36864
    int co = t & 63;
    int c  = (t >> 6) & 63;
    int k  = t >> 12;                           // 0..8
    wT[t] = Wsrc[(co * 64 + c) * 9 + k];
}

// ---------------------------------------------------------------------------
// Kernel X: transpose x NCHW -> NHWC. XCD swizzle (b = bid&7) so image b's
// xt lands in the same XCD L2 that deform_main will read it from.
// ---------------------------------------------------------------------------
__global__ __launch_bounds__(256) void xpose_kernel(const float* __restrict__ x,
                                                    float* __restrict__ xt) {
    __shared__ float T[64][65];                 // pad: conflict-free col reads
    int bid   = blockIdx.x;                     // 1152
    int b     = bid & 7;                        // XCD-affine
    int pbase = (bid >> 3) * 64;
    int t     = threadIdx.x;
    int pl    = t & 63;
    int q     = t >> 6;                         // 0..3
#pragma unroll
    for (int i = 0; i < 16; ++i) {
        int c = q * 16 + i;
        T[c][pl] = x[((size_t)b * 64 + c) * HW + pbase + pl];
    }
    __syncthreads();
#pragma unroll
    for (int i = 0; i < 16; ++i) {
        int p = q * 16 + i;
        xt[((size_t)(b * HW + pbase + p)) * 64 + pl] = T[pl][p];
    }
}

// ---------------------------------------------------------------------------
// Kernel A: offset conv, c split 4 ways; XCD swizzle for x locality.
// ---------------------------------------------------------------------------
__global__ __launch_bounds__(256) void offs_kernel(const float* __restrict__ x,
                                                   const float* __restrict__ ow,
                                                   const float* __restrict__ ob,
                                                   float* __restrict__ off) {
    __shared__ float red[3][18][64];
    int bid   = blockIdx.x;                     // 1152
    int b     = bid & 7;                        // XCD-affine
    int pbase = (bid >> 3) * 64;
    int t     = threadIdx.x;
    int pl    = t & 63;
    int cq    = __builtin_amdgcn_readfirstlane(t >> 6);   // wave-uniform 0..3
    int rem   = pbase + pl;
    int h     = rem / WW;
    int w     = rem % WW;

    float acc[18];
#pragma unroll
    for (int j = 0; j < 18; ++j) acc[j] = (cq == 0) ? ob[j] : 0.f;

    const float* xb = x + ((size_t)b * CIN + cq * 16) * HW;

    for (int c = 0; c < 16; ++c) {
        float v[9];
#pragma unroll
        for (int r = 0; r < 3; ++r) {
            int  iy = h - 1 + r;
            bool ry = (iy >= 0) && (iy < HH);
#pragma unroll
            for (int s = 0; s < 3; ++s) {
                int  ix = w - 1 + s;
                bool cx = (ix >= 0) && (ix < WW);
                v[r * 3 + s] = (ry && cx) ? xb[c * HW + iy * WW + ix] : 0.f;
            }
        }
#pragma unroll
        for (int j = 0; j < 18; ++j) {
            const float* wp = ow + ((j * 64) + (cq * 16 + c)) * 9;  // scalar addr
            float a = acc[j];
#pragma unroll
            for (int q = 0; q < 9; ++q) a = fmaf(v[q], wp[q], a);
            acc[j] = a;
        }
    }

    if (cq != 0) {
#pragma unroll
        for (int j = 0; j < 18; ++j) red[cq - 1][j][pl] = acc[j];
    }
    __syncthreads();
    if (cq == 0) {
#pragma unroll
        for (int j = 0; j < 18; ++j) {
            float a = acc[j] + red[0][j][pl] + red[1][j][pl] + red[2][j][pl];
            off[((size_t)b * 18 + j) * HW + rem] = a;
        }
    }
}

// ---------------------------------------------------------------------------
// Kernel B: implicit GEMM, 64 px x 64 co per block. XCD swizzle: each XCD
// owns one image -> xt working set (2.36 MB) fits its 4 MiB L2.
// ---------------------------------------------------------------------------
__global__ __launch_bounds__(256) void deform_main(const float* __restrict__ xt,
                                                   const float* __restrict__ wT,
                                                   const float* __restrict__ bias,
                                                   const float* __restrict__ off,
                                                   float* __restrict__ out) {
    __shared__ float S[64][64];     // [c][px]
    __shared__ float Wk[64][64];    // [c][co]

    int bid   = blockIdx.x;                     // 1152
    int b     = bid & 7;                        // XCD-affine: image per XCD
    int pbase = (bid >> 3) * 64;
    int t     = threadIdx.x;

    // sampling role
    int pl = t & 63;
    int cg = __builtin_amdgcn_readfirstlane(t >> 6);   // 0..3 (16 c each)
    int c0 = cg * 16;
    int px = pbase + pl;
    int h  = px / WW;
    int w  = px % WW;
    const float* offb = off + (size_t)b * 18 * HW + px;
    const float* xb   = xt + (size_t)b * HW * 64;

    // prefetch all 18 offsets (hides the per-k load latency)
    float offy[9], offx[9];
#pragma unroll
    for (int k = 0; k < 9; ++k) {
        offy[k] = offb[(2 * k) * HW];
        offx[k] = offb[(2 * k + 1) * HW];
    }

    // gemm role: 4 co x 4 px per thread
    int px4 = (t & 15) * 4;
    int co4 = (t >> 4) * 4;

    float acc[4][4];
#pragma unroll
    for (int i = 0; i < 4; ++i)
#pragma unroll
        for (int j = 0; j < 4; ++j) acc[i][j] = 0.f;

    for (int k = 0; k < 9; ++k) {
        // ---- phase 1: sample S[c0..c0+16)[pl] ----
        int   r = k / 3, s = k - r * 3;
        float sy = (float)(h + r) + offy[k];   // ref: h + 1 + (r-1) + off
        float sx = (float)(w + s) + offx[k];
        float fy = floorf(sy), fx = floorf(sx);
        int   y0 = (int)fy, x0 = (int)fx;
        int   y1 = y0 + 1, x1 = x0 + 1;
        float wy1 = sy - fy, wx1 = sx - fx;
        float wy0 = 1.f - wy1, wx0 = 1.f - wx1;

        float m00 = (y0 >= 0 && y0 < HH && x0 >= 0 && x0 < WW) ? 1.f : 0.f;
        float m01 = (y0 >= 0 && y0 < HH && x1 >= 0 && x1 < WW) ? 1.f : 0.f;
        float m10 = (y1 >= 0 && y1 < HH && x0 >= 0 && x0 < WW) ? 1.f : 0.f;
        float m11 = (y1 >= 0 && y1 < HH && x1 >= 0 && x1 < WW) ? 1.f : 0.f;

        int cy0 = min(max(y0, 0), HH - 1), cy1 = min(max(y1, 0), HH - 1);
        int cx0 = min(max(x0, 0), WW - 1), cx1 = min(max(x1, 0), WW - 1);
        float w00 = wy0 * wx0 * m00, w01 = wy0 * wx1 * m01;
        float w10 = wy1 * wx0 * m10, w11 = wy1 * wx1 * m11;

        const float* p00 = xb + (size_t)(cy0 * WW + cx0) * 64 + c0;
        const float* p01 = xb + (size_t)(cy0 * WW + cx1) * 64 + c0;
        const float* p10 = xb + (size_t)(cy1 * WW + cx0) * 64 + c0;
        const float* p11 = xb + (size_t)(cy1 * WW + cx1) * 64 + c0;

#pragma unroll
        for (int i = 0; i < 4; ++i) {           // 4 c per chunk, 4 chunks = 16 c
            float4 v00 = *(const float4*)(p00 + i * 4);
            float4 v01 = *(const float4*)(p01 + i * 4);
            float4 v10 = *(const float4*)(p10 + i * 4);
            float4 v11 = *(const float4*)(p11 + i * 4);
            S[c0 + i * 4 + 0][pl] = w00 * v00.x + w01 * v01.x + w10 * v10.x + w11 * v11.x;
            S[c0 + i * 4 + 1][pl] = w00 * v00.y + w01 * v01.y + w10 * v10.y + w11 * v11.y;
            S[c0 + i * 4 + 2][pl] = w00 * v00.z + w01 * v01.z + w10 * v10.z + w11 * v11.z;
            S[c0 + i * 4 + 3][pl] = w00 * v00.w + w01 * v01.w + w10 * v10.w + w11 * v11.w;
        }

        // ---- stage Wk: contiguous lanes (1 KB/wave global burst, minimal
        //      b128 LDS write aliasing; old t*4+i pattern was 4-banks-only) ----
        {
            const float4* src = (const float4*)(wT + (size_t)k * 4096);
            float4*       dst = (float4*)&Wk[0][0];
#pragma unroll
            for (int i = 0; i < 4; ++i) dst[i * 256 + t] = src[i * 256 + t];
        }
        __syncthreads();

        // ---- phase 2: GEMM over cc ----
#pragma unroll 4
        for (int cc = 0; cc < 64; ++cc) {
            float4 a  = *(const float4*)&S[cc][px4];
            float4 wv = *(const float4*)&Wk[cc][co4];
            acc[0][0] = fmaf(wv.x, a.x, acc[0][0]);
            acc[0][1] = fmaf(wv.x, a.y, acc[0][1]);
            acc[0][2] = fmaf(wv.x, a.z, acc[0][2]);
            acc[0][3] = fmaf(wv.x, a.w, acc[0][3]);
            acc[1][0] = fmaf(wv.y, a.x, acc[1][0]);
            acc[1][1] = fmaf(wv.y, a.y, acc[1][1]);
            acc[1][2] = fmaf(wv.y, a.z, acc[1][2]);
            acc[1][3] = fmaf(wv.y, a.w, acc[1][3]);
            acc[2][0] = fmaf(wv.z, a.x, acc[2][0]);
            acc[2][1] = fmaf(wv.z, a.y, acc[2][1]);
            acc[2][2] = fmaf(wv.z, a.z, acc[2][2]);
            acc[2][3] = fmaf(wv.z, a.w, acc[2][3]);
            acc[3][0] = fmaf(wv.w, a.x, acc[3][0]);
            acc[3][1] = fmaf(wv.w, a.y, acc[3][1]);
            acc[3][2] = fmaf(wv.w, a.z, acc[3][2]);
            acc[3][3] = fmaf(wv.w, a.w, acc[3][3]);
        }
        __syncthreads();
    }

    // ---- epilogue ----
#pragma unroll
    for (int i = 0; i < 4; ++i) {
        int   co = co4 + i;
        float bv = bias[co];
        float4 r;
        r.x = acc[i][0] + bv;
        r.y = acc[i][1] + bv;
        r.z = acc[i][2] + bv;
        r.w = acc[i][3] + bv;
        *(float4*)(out + ((size_t)b * COUT + co) * HW + pbase + px4) = r;
    }
}

// ---------------------------------------------------------------------------
extern "C" void kernel_launch(void* const* d_in, const int* in_sizes, int n_in,
                              void* d_out, int out_size, void* d_ws, size_t ws_size,
                              hipStream_t stream) {
    const float* x      = (const float*)d_in[0];   // 8*64*96*96
    const float* weight = (const float*)d_in[1];   // 64*64*3*3
    const float* bias   = (const float*)d_in[2];   // 64
    const float* off_w  = (const float*)d_in[3];   // 18*64*3*3
    const float* off_b  = (const float*)d_in[4];   // 18
    float* out = (float*)d_out;                    // 8*64*96*96

    float* offbuf = (float*)d_ws;                        // 1,327,104 floats
    float* wT     = offbuf + (size_t)NB * 18 * HW;       // 36,864 floats
    float* xt     = wT + 9 * 64 * 64;                    // 4,718,592 floats

    hipLaunchKernelGGL(wtrans_kernel, dim3(144),  dim3(256), 0, stream, weight, wT);
    hipLaunchKernelGGL(xpose_kernel,  dim3(1152), dim3(256), 0, stream, x, xt);
    hipLaunchKernelGGL(offs_kernel,   dim3(1152), dim3(256), 0, stream, x, off_w, off_b, offbuf);
    hipLaunchKernelGGL(deform_main,   dim3(1152), dim3(256), 0, stream, xt, wT, bias, offbuf, out);
}

// Round 4
// 161.744 us; speedup vs baseline: 6.8551x; 1.4901x over previous
//
#include <hip/hip_runtime.h>

#define HH 96
#define WW 96
#define HW 9216
#define CIN 64
#define COUT 64
#define NB 8

typedef __bf16 bf16x8 __attribute__((ext_vector_type(8)));
typedef float  f32x4  __attribute__((ext_vector_type(4)));

__device__ __forceinline__ unsigned short f2bf_bits(float f) {
    unsigned u = __float_as_uint(f);
    unsigned r = u + 0x7FFFu + ((u >> 16) & 1u);     // RNE
    return (unsigned short)(r >> 16);
}
__device__ __forceinline__ float bf2f(unsigned short s) {
    return __uint_as_float(((unsigned)s) << 16);
}

// ---------------------------------------------------------------------------
// Kernel 1: xcvt + prep (fused). Blocks 0..1151 convert x NCHW fp32 ->
// xt NHWC bf16 (thread owns 16 c of one pixel -> no LDS needed).
// Blocks < 216 additionally build wTb [tap][co][c] bf16 and
// owTb [j(32)][tap*64+c] bf16 (rows 18..31 zeroed).
// ---------------------------------------------------------------------------
__global__ __launch_bounds__(256) void xcvt_prep(const float* __restrict__ x,
                                                 const float* __restrict__ weight,
                                                 const float* __restrict__ off_w,
                                                 unsigned short* __restrict__ xt,
                                                 unsigned short* __restrict__ wTb,
                                                 unsigned short* __restrict__ owTb) {
    int bid   = blockIdx.x;                 // 1152
    int t     = threadIdx.x;
    int b     = bid & 7;                    // XCD-affine
    int pbase = (bid >> 3) * 64;
    int pl    = t & 63;
    int q     = t >> 6;                     // c-group 0..3
    int p     = pbase + pl;

    const float* xp = x + ((size_t)(b * 64 + q * 16)) * HW + p;
    unsigned short hbits[16];
#pragma unroll
    for (int i = 0; i < 16; ++i) hbits[i] = f2bf_bits(xp[(size_t)i * HW]);

    uint4 w0, w1;
    w0.x = hbits[0]  | (hbits[1]  << 16);
    w0.y = hbits[2]  | (hbits[3]  << 16);
    w0.z = hbits[4]  | (hbits[5]  << 16);
    w0.w = hbits[6]  | (hbits[7]  << 16);
    w1.x = hbits[8]  | (hbits[9]  << 16);
    w1.y = hbits[10] | (hbits[11] << 16);
    w1.z = hbits[12] | (hbits[13] << 16);
    w1.w = hbits[14] | (hbits[15] << 16);
    unsigned short* dst = xt + ((size_t)(b * HW + p)) * 64 + q * 16;
    *(uint4*)dst       = w0;
    *(uint4*)(dst + 8) = w1;

    // ---- prep (first 216 blocks): 216*256 = 55296 = 36864 + 18432 ----
    if (bid < 216) {
        int i = bid * 256 + t;
        if (i < 36864) {
            int tap = i >> 12;
            int co  = (i >> 6) & 63;
            int c   = i & 63;
            wTb[i] = f2bf_bits(weight[(co * 64 + c) * 9 + tap]);
        } else {
            int f  = i - 36864;             // f < 18432 = 32*576
            int j  = f / 576;
            int kk = f - j * 576;
            int tap = kk >> 6;
            int c   = kk & 63;
            owTb[f] = (j < 18) ? f2bf_bits(off_w[((j * 64 + c) * 9) + tap]) : (unsigned short)0;
        }
    }
}

// ---------------------------------------------------------------------------
// Kernel 2: offset conv as implicit GEMM with bf16 MFMA.
// Block = 64 px; per tap: stage zero-padded patch S[64px][64c] bf16 in LDS,
// MFMA against owTb (B[n=j][k], read from global/L1). N=18 -> 2 j-tiles,
// tile 1 stores only j=16,17.
// ---------------------------------------------------------------------------
__global__ __launch_bounds__(256, 4) void offs_mfma(const unsigned short* __restrict__ xt,
                                                    const unsigned short* __restrict__ owTb,
                                                    const float* __restrict__ ob,
                                                    float* __restrict__ off) {
    __shared__ unsigned short S[64 * 72];   // [px][c], pad 72 (144 B rows)

    int bid   = blockIdx.x;                 // 1152
    int t     = threadIdx.x;
    int b     = bid & 7;
    int pbase = (bid >> 3) * 64;

    int pl = t & 63;                        // staging px
    int cg = t >> 6;                        // staging c-group (16 c)
    int px = pbase + pl;
    int h  = px / WW;
    int w  = px - h * WW;

    int ln = t & 15;                        // MFMA lane&15
    int qd = (t >> 4) & 3;                  // MFMA quad
    int pt = t >> 6;                        // wave = px-tile

    f32x4 accj[2] = {{0.f, 0.f, 0.f, 0.f}, {0.f, 0.f, 0.f, 0.f}};

    const unsigned short* xb = xt + (size_t)b * HW * 64;

    for (int tap = 0; tap < 9; ++tap) {
        int r  = tap / 3, s = tap - r * 3;
        int iy = h - 1 + r, ix = w - 1 + s;
        bool valid = (iy >= 0) & (iy < HH) & (ix >= 0) & (ix < WW);
        uint4 va = {0u, 0u, 0u, 0u}, vb = {0u, 0u, 0u, 0u};
        if (valid) {
            const uint4* p = (const uint4*)(xb + ((size_t)(iy * WW + ix)) * 64 + cg * 16);
            va = p[0];
            vb = p[1];
        }
        *(uint4*)&S[pl * 72 + cg * 16]     = va;
        *(uint4*)&S[pl * 72 + cg * 16 + 8] = vb;
        __syncthreads();

        bf16x8 a0 = *(const bf16x8*)&S[(pt * 16 + ln) * 72 + qd * 8];
        bf16x8 a1 = *(const bf16x8*)&S[(pt * 16 + ln) * 72 + 32 + qd * 8];
#pragma unroll
        for (int jt = 0; jt < 2; ++jt) {
            const unsigned short* brow = owTb + (size_t)(jt * 16 + ln) * 576 + tap * 64 + qd * 8;
            bf16x8 b0 = *(const bf16x8*)brow;
            bf16x8 b1 = *(const bf16x8*)(brow + 32);
            accj[jt] = __builtin_amdgcn_mfma_f32_16x16x32_bf16(a0, b0, accj[jt], 0, 0, 0);
            accj[jt] = __builtin_amdgcn_mfma_f32_16x16x32_bf16(a1, b1, accj[jt], 0, 0, 0);
        }
        __syncthreads();
    }

    // epilogue: D col = j, row = px (quad*4 + reg)
    int pxo = pbase + pt * 16 + qd * 4;
    {
        float bv = ob[ln];
        float4 st;
        st.x = accj[0].x + bv; st.y = accj[0].y + bv;
        st.z = accj[0].z + bv; st.w = accj[0].w + bv;
        *(float4*)(off + ((size_t)(b * 18 + ln)) * HW + pxo) = st;
    }
    if (ln < 2) {
        int   j  = 16 + ln;
        float bv = ob[j];
        float4 st;
        st.x = accj[1].x + bv; st.y = accj[1].y + bv;
        st.z = accj[1].z + bv; st.w = accj[1].w + bv;
        *(float4*)(off + ((size_t)(b * 18 + j)) * HW + pxo) = st;
    }
}

// ---------------------------------------------------------------------------
// Kernel 3: deformable conv main. Per tap: bilinear-sample S[64px][64c] bf16
// into LDS, stage Wk[64co][64c] bf16, MFMA (wave = co-tile, 4 px-tiles).
// ---------------------------------------------------------------------------
__global__ __launch_bounds__(256, 4) void deform_main(const unsigned short* __restrict__ xt,
                                                      const unsigned short* __restrict__ wTb,
                                                      const float* __restrict__ bias,
                                                      const float* __restrict__ off,
                                                      float* __restrict__ out) {
    __shared__ unsigned short S[64 * 72];   // [px][c]
    __shared__ unsigned short Wk[64 * 72];  // [co][c]

    int bid   = blockIdx.x;                 // 1152
    int t     = threadIdx.x;
    int b     = bid & 7;                    // image per XCD
    int pbase = (bid >> 3) * 64;

    int pl = t & 63;
    int cg = t >> 6;                        // staging c-group
    int px = pbase + pl;
    int h  = px / WW;
    int w  = px - h * WW;

    int ln = t & 15;
    int qd = (t >> 4) & 3;
    int ct = t >> 6;                        // wave = co-tile

    const unsigned short* xb = xt + (size_t)b * HW * 64;
    const float* offb = off + (size_t)b * 18 * HW + px;

    float offy[9], offx[9];
#pragma unroll
    for (int k = 0; k < 9; ++k) {
        offy[k] = offb[(2 * k) * HW];
        offx[k] = offb[(2 * k + 1) * HW];
    }

    f32x4 acc[4] = {{0.f,0.f,0.f,0.f},{0.f,0.f,0.f,0.f},{0.f,0.f,0.f,0.f},{0.f,0.f,0.f,0.f}};

    for (int tap = 0; tap < 9; ++tap) {
        // ---- sample 16 c (bf16 in, fp32 math, bf16 out) ----
        int   r = tap / 3, s = tap - r * 3;
        float sy = (float)(h + r) + offy[tap];
        float sx = (float)(w + s) + offx[tap];
        float fy = floorf(sy), fx = floorf(sx);
        int   y0 = (int)fy, x0 = (int)fx;
        int   y1 = y0 + 1, x1 = x0 + 1;
        float wy1 = sy - fy, wx1 = sx - fx;
        float wy0 = 1.f - wy1, wx0 = 1.f - wx1;

        float m00 = (y0 >= 0 && y0 < HH && x0 >= 0 && x0 < WW) ? 1.f : 0.f;
        float m01 = (y0 >= 0 && y0 < HH && x1 >= 0 && x1 < WW) ? 1.f : 0.f;
        float m10 = (y1 >= 0 && y1 < HH && x0 >= 0 && x0 < WW) ? 1.f : 0.f;
        float m11 = (y1 >= 0 && y1 < HH && x1 >= 0 && x1 < WW) ? 1.f : 0.f;

        int cy0 = min(max(y0, 0), HH - 1), cy1 = min(max(y1, 0), HH - 1);
        int cx0 = min(max(x0, 0), WW - 1), cx1 = min(max(x1, 0), WW - 1);
        float w00 = wy0 * wx0 * m00, w01 = wy0 * wx1 * m01;
        float w10 = wy1 * wx0 * m10, w11 = wy1 * wx1 * m11;

        const uint4* p00 = (const uint4*)(xb + ((size_t)(cy0 * WW + cx0)) * 64 + cg * 16);
        const uint4* p01 = (const uint4*)(xb + ((size_t)(cy0 * WW + cx1)) * 64 + cg * 16);
        const uint4* p10 = (const uint4*)(xb + ((size_t)(cy1 * WW + cx0)) * 64 + cg * 16);
        const uint4* p11 = (const uint4*)(xb + ((size_t)(cy1 * WW + cx1)) * 64 + cg * 16);
        uint4 c00[2] = {p00[0], p00[1]};
        uint4 c01[2] = {p01[0], p01[1]};
        uint4 c10[2] = {p10[0], p10[1]};
        uint4 c11[2] = {p11[0], p11[1]};

        unsigned short ov[16];
#pragma unroll
        for (int g = 0; g < 2; ++g) {
            const unsigned short* q00 = (const unsigned short*)&c00[g];
            const unsigned short* q01 = (const unsigned short*)&c01[g];
            const unsigned short* q10 = (const unsigned short*)&c10[g];
            const unsigned short* q11 = (const unsigned short*)&c11[g];
#pragma unroll
            for (int i = 0; i < 8; ++i) {
                float v = w00 * bf2f(q00[i]) + w01 * bf2f(q01[i])
                        + w10 * bf2f(q10[i]) + w11 * bf2f(q11[i]);
                ov[g * 8 + i] = f2bf_bits(v);
            }
        }
        uint4 s0, s1;
        s0.x = ov[0]  | (ov[1]  << 16); s0.y = ov[2]  | (ov[3]  << 16);
        s0.z = ov[4]  | (ov[5]  << 16); s0.w = ov[6]  | (ov[7]  << 16);
        s1.x = ov[8]  | (ov[9]  << 16); s1.y = ov[10] | (ov[11] << 16);
        s1.z = ov[12] | (ov[13] << 16); s1.w = ov[14] | (ov[15] << 16);
        *(uint4*)&S[pl * 72 + cg * 16]     = s0;
        *(uint4*)&S[pl * 72 + cg * 16 + 8] = s1;

        // ---- stage Wk[64co][64c] for this tap (8 KB) ----
        {
            const uint4* wsrc = (const uint4*)(wTb + (size_t)tap * 4096);
            uint4 a  = wsrc[2 * t];
            uint4 b2 = wsrc[2 * t + 1];
            int co = t >> 2, c0 = (t & 3) * 16;
            *(uint4*)&Wk[co * 72 + c0]     = a;
            *(uint4*)&Wk[co * 72 + c0 + 8] = b2;
        }
        __syncthreads();

        // ---- MFMA: wave ct covers co-tile ct, all 4 px-tiles ----
        bf16x8 b0 = *(const bf16x8*)&Wk[(ct * 16 + ln) * 72 + qd * 8];
        bf16x8 b1 = *(const bf16x8*)&Wk[(ct * 16 + ln) * 72 + 32 + qd * 8];
#pragma unroll
        for (int pt = 0; pt < 4; ++pt) {
            bf16x8 a0 = *(const bf16x8*)&S[(pt * 16 + ln) * 72 + qd * 8];
            bf16x8 a1 = *(const bf16x8*)&S[(pt * 16 + ln) * 72 + 32 + qd * 8];
            acc[pt] = __builtin_amdgcn_mfma_f32_16x16x32_bf16(a0, b0, acc[pt], 0, 0, 0);
            acc[pt] = __builtin_amdgcn_mfma_f32_16x16x32_bf16(a1, b1, acc[pt], 0, 0, 0);
        }
        __syncthreads();
    }

    // ---- epilogue: D col = co, row = px (quad*4 + reg) ----
    int   co = ct * 16 + ln;
    float bv = bias[co];
    float* ob2 = out + ((size_t)(b * 64 + co)) * HW + pbase + qd * 4;
#pragma unroll
    for (int pt = 0; pt < 4; ++pt) {
        float4 st;
        st.x = acc[pt].x + bv; st.y = acc[pt].y + bv;
        st.z = acc[pt].z + bv; st.w = acc[pt].w + bv;
        *(float4*)(ob2 + pt * 16) = st;
    }
}

// ---------------------------------------------------------------------------
extern "C" void kernel_launch(void* const* d_in, const int* in_sizes, int n_in,
                              void* d_out, int out_size, void* d_ws, size_t ws_size,
                              hipStream_t stream) {
    const float* x      = (const float*)d_in[0];   // 8*64*96*96
    const float* weight = (const float*)d_in[1];   // 64*64*3*3
    const float* bias   = (const float*)d_in[2];   // 64
    const float* off_w  = (const float*)d_in[3];   // 18*64*3*3
    const float* off_b  = (const float*)d_in[4];   // 18
    float* out = (float*)d_out;

    float*          offbuf = (float*)d_ws;                         // 1,327,104 f
    unsigned short* xt     = (unsigned short*)(offbuf + 1327104);  // 4,718,592 bf16
    unsigned short* wTb    = xt + 4718592;                         // 36,864 bf16
    unsigned short* owTb   = wTb + 36864;                          // 18,432 bf16

    hipLaunchKernelGGL(xcvt_prep,   dim3(1152), dim3(256), 0, stream,
                       x, weight, off_w, xt, wTb, owTb);
    hipLaunchKernelGGL(offs_mfma,   dim3(1152), dim3(256), 0, stream,
                       xt, owTb, off_b, offbuf);
    hipLaunchKernelGGL(deform_main, dim3(1152), dim3(256), 0, stream,
                       xt, wTb, bias, offbuf, out);
}